// Round 11
// baseline (262.303 us; speedup 1.0000x reference)
//
#include <hip/hip_runtime.h>

// ============================================================================
// R11 = MEASUREMENT ROUND. Kernels are byte-identical to R10.
// score_kernel is launched 4x (idempotent: deterministic pure function,
// rewrites identical values). dur_us(R11) - dur_us(R10) = 3 x score duration.
// ============================================================================

#define D 128
#define HDIM 256
#define NB 8            // batch size (fixed by setup_inputs)
#define NSHARD 16       // topk shards per row
#define CPS 16          // candidates per shard
#define NCAND (NSHARD * CPS)   // 256 candidates per row
#define PHW 16          // phW row stride (floats): [0..7]=ph, [8]=W2

typedef short bf16x8 __attribute__((ext_vector_type(8)));
typedef float f32x4 __attribute__((ext_vector_type(4)));

__device__ __forceinline__ unsigned short f2bf(float x) {
    unsigned u = __float_as_uint(x);
    unsigned r = u + 0x7FFF + ((u >> 16) & 1);   // RNE (finite data)
    return (unsigned short)(r >> 16);
}
__device__ __forceinline__ bf16x8 pack_bf8(float4 u, float4 v) {
    union { bf16x8 v8; unsigned short s[8]; } r;
    r.s[0] = f2bf(u.x); r.s[1] = f2bf(u.y); r.s[2] = f2bf(u.z); r.s[3] = f2bf(u.w);
    r.s[4] = f2bf(v.x); r.s[5] = f2bf(v.y); r.s[6] = f2bf(v.z); r.s[7] = f2bf(v.w);
    return r.v8;
}

// key = (ordered_float << 32) | (0xFFFFFFFF - idx): max == (max val, min idx)
__device__ __forceinline__ unsigned long long sk_encode(float v, int idx) {
    unsigned u = __float_as_uint(v);
    u = (u & 0x80000000u) ? ~u : (u | 0x80000000u);
    return ((unsigned long long)u << 32) | (unsigned)(0xFFFFFFFFu - (unsigned)idx);
}
__device__ __forceinline__ float sk_val(unsigned long long key) {
    const unsigned u = (unsigned)(key >> 32);
    return (u & 0x80000000u) ? __uint_as_float(u & 0x7FFFFFFFu) : __uint_as_float(~u);
}
__device__ __forceinline__ int sk_idx(unsigned long long key) {
    return (int)(0xFFFFFFFFu - (unsigned)(key & 0xFFFFFFFFu));
}
__device__ __forceinline__ unsigned long long wave_max64(unsigned long long m) {
#pragma unroll
    for (int s = 32; s > 0; s >>= 1) {
        const unsigned long long o = __shfl_xor(m, s, 64);
        if (o > m) m = o;
    }
    return m;
}

// ---------------------------------------------------------------------------
// K1: prep. blocks 0..7: ph row b -> phW[h][b] (+W2 -> phW[h][8] from b==0).
//     blocks 8..39: w1tt = bf16(W1t^T), 4 k-cols each.
// ---------------------------------------------------------------------------
__global__ __launch_bounds__(HDIM) void prep_kernel(
        const int* __restrict__ head, const int* __restrict__ relation,
        const float* __restrict__ ent_emb, const float* __restrict__ rel_emb,
        const float* __restrict__ W1, const float* __restrict__ b1,
        const float* __restrict__ W2, float* __restrict__ phW,
        unsigned short* __restrict__ w1tt) {
    const int w = blockIdx.x;
    const int tid = threadIdx.x;
    if (w < NB) {
        const int b = w;
        const long hidx = head[b];
        const long ridx = relation[b];
        const float* hrow = ent_emb + hidx * D;
        const float* rrow = rel_emb + ridx * D;
        float acc = b1[tid];
#pragma unroll 8
        for (int d = 0; d < D; ++d)
            acc += hrow[d] * W1[d * HDIM + tid];       // coalesced across tid
#pragma unroll 8
        for (int d = 0; d < D; ++d)
            acc += rrow[d] * W1[(D + d) * HDIM + tid];
        phW[tid * PHW + b] = acc;
        if (b == 0) phW[tid * PHW + 8] = W2[tid];
    } else {
        const int k0 = (w - NB) * 4;
        const float* w1t = W1 + 2 * D * HDIM;
        unsigned short pk[4];
#pragma unroll
        for (int j = 0; j < 4; ++j)
            pk[j] = f2bf(w1t[(k0 + j) * HDIM + tid]);  // coalesced across tid
        *(ushort4*)(w1tt + tid * D + k0) = make_ushort4(pk[0], pk[1], pk[2], pk[3]);
    }
}

// ---------------------------------------------------------------------------
// K2: MFMA score, zero LDS/barriers, 2 A-tiles per wave, register-pipelined.
// (R10 body, unchanged — this is the kernel under measurement.)
// ---------------------------------------------------------------------------
__global__ __launch_bounds__(256) void score_kernel(
        const float* __restrict__ ent_emb, const unsigned short* __restrict__ w1tt,
        const float* __restrict__ phW, float* __restrict__ scores, int E) {
    const int tid = threadIdx.x;
    const int lane = tid & 63;
    const int wave = tid >> 6;
    const int lm = lane & 15;
    const int q = lane >> 4;
    const int base_e = blockIdx.x * 128 + wave * 32;

    const float* arow0 = ent_emb + (size_t)min(base_e + lm, E - 1) * D;
    const float* arow1 = ent_emb + (size_t)min(base_e + 16 + lm, E - 1) * D;
    bf16x8 aF0[4], aF1[4];
#pragma unroll
    for (int kk = 0; kk < 4; ++kk) {
        const float4 u0 = *(const float4*)(arow0 + kk * 32 + q * 8);
        const float4 v0 = *(const float4*)(arow0 + kk * 32 + q * 8 + 4);
        aF0[kk] = pack_bf8(u0, v0);
        const float4 u1 = *(const float4*)(arow1 + kk * 32 + q * 8);
        const float4 v1 = *(const float4*)(arow1 + kk * 32 + q * 8 + 4);
        aF1[kk] = pack_bf8(u1, v1);
    }

    float sp0[NB * 4], sp1[NB * 4];
#pragma unroll
    for (int i = 0; i < NB * 4; ++i) { sp0[i] = 0.f; sp1[i] = 0.f; }

    const unsigned short* wb = w1tt + (size_t)lm * D + q * 8;

    bf16x8 bFc[4];
#pragma unroll
    for (int kk = 0; kk < 4; ++kk)
        bFc[kk] = *(const bf16x8*)(wb + kk * 32);

#pragma unroll
    for (int t = 0; t < 16; ++t) {
        bf16x8 bFn[4];
        if (t < 15) {
#pragma unroll
            for (int kk = 0; kk < 4; ++kk)
                bFn[kk] = *(const bf16x8*)(wb + (size_t)(t + 1) * 16 * D + kk * 32);
        }
        const int h = t * 16 + lm;
        const float4 pa = *(const float4*)(phW + h * PHW);
        const float4 pb = *(const float4*)(phW + h * PHW + 4);
        const float w2v = phW[h * PHW + 8];

        f32x4 acc0 = (f32x4){0.f, 0.f, 0.f, 0.f};
        f32x4 acc1 = (f32x4){0.f, 0.f, 0.f, 0.f};
#pragma unroll
        for (int kk = 0; kk < 4; ++kk) {
            acc0 = __builtin_amdgcn_mfma_f32_16x16x32_bf16(aF0[kk], bFc[kk], acc0, 0, 0, 0);
            acc1 = __builtin_amdgcn_mfma_f32_16x16x32_bf16(aF1[kk], bFc[kk], acc1, 0, 0, 0);
        }

        const float phv[8] = {pa.x, pa.y, pa.z, pa.w, pb.x, pb.y, pb.z, pb.w};
#pragma unroll
        for (int b = 0; b < NB; ++b)
#pragma unroll
            for (int r = 0; r < 4; ++r) {
                sp0[b * 4 + r] += fmaxf(phv[b] + acc0[r], 0.f) * w2v;
                sp1[b * 4 + r] += fmaxf(phv[b] + acc1[r], 0.f) * w2v;
            }

        if (t < 15) {
#pragma unroll
            for (int kk = 0; kk < 4; ++kk) bFc[kk] = bFn[kk];
        }
    }

#pragma unroll
    for (int m = 1; m <= 8; m <<= 1) {
#pragma unroll
        for (int i = 0; i < NB * 4; ++i) {
            sp0[i] += __shfl_xor(sp0[i], m, 64);
            sp1[i] += __shfl_xor(sp1[i], m, 64);
        }
    }
    if (lm == 0) {
#pragma unroll
        for (int r = 0; r < 4; ++r) {
            const int e0 = base_e + q * 4 + r;
            const int e1 = base_e + 16 + q * 4 + r;
            if (e0 < E) {
#pragma unroll
                for (int b = 0; b < NB; ++b)
                    scores[(size_t)b * E + e0] = sp0[b * 4 + r];
            }
            if (e1 < E) {
#pragma unroll
                for (int b = 0; b < NB; ++b)
                    scores[(size_t)b * E + e1] = sp1[b * 4 + r];
            }
        }
    }
}

// ---------------------------------------------------------------------------
// K3: shard top-16 + exact fp32 rescore. 128 blocks = 8 rows x 16 shards.
// ---------------------------------------------------------------------------
__global__ __launch_bounds__(256) void topk_rescore_kernel(
        const float* __restrict__ scores, int E,
        const float* __restrict__ ent_emb, const float* __restrict__ W1,
        const float* __restrict__ phW, const float* __restrict__ b2,
        unsigned long long* __restrict__ cand_exact) {
    const int b = blockIdx.x >> 4;
    const int s = blockIdx.x & 15;
    const int tid = threadIdx.x;
    const int lane = tid & 63;
    const int wave = tid >> 6;

    __shared__ unsigned long long cl[4 * CPS];
    __shared__ unsigned long long candk[CPS];
    __shared__ int eIdxs[CPS];
    __shared__ float entR[CPS][D];                 // 8 KB
    __shared__ float red[4][CPS];

    {
        const int shard = (E + NSHARD - 1) / NSHARD;
        const int start = s * shard;
        const int end = min(E, start + shard);
        const float* row = scores + (size_t)b * E;

        unsigned long long keys[CPS];
#pragma unroll
        for (int i = 0; i < CPS; ++i) keys[i] = 0ull;

        for (int e = start + tid; e < end; e += 256) {
            unsigned long long key = sk_encode(row[e], e);
            if (key > keys[CPS - 1]) {
#pragma unroll
                for (int j = 0; j < CPS; ++j) {
                    const bool gt = key > keys[j];
                    const unsigned long long mx = gt ? key : keys[j];
                    key = gt ? keys[j] : key;
                    keys[j] = mx;
                }
            }
        }
        for (int r = 0; r < CPS; ++r) {
            const unsigned long long m = wave_max64(keys[0]);
            if (keys[0] == m) {
#pragma unroll
                for (int j = 0; j < CPS - 1; ++j) keys[j] = keys[j + 1];
                keys[CPS - 1] = 0ull;
            }
            if (lane == 0) cl[wave * CPS + r] = m;
        }
        __syncthreads();
        if (wave == 0) {
            unsigned long long v = cl[lane];       // 64 candidates
            for (int r = 0; r < CPS; ++r) {
                const unsigned long long m = wave_max64(v);
                if (v == m) v = 0ull;
                if (lane == 0) candk[r] = m;
            }
        }
        __syncthreads();
    }

    if (tid < CPS) eIdxs[tid] = sk_idx(candk[tid]);
    __syncthreads();
    for (int t = tid; t < CPS * (D / 4); t += 256) {
        const int row = t >> 5, c4 = (t & 31) * 4;
        *(float4*)(&entR[row][c4]) =
            *(const float4*)(ent_emb + (size_t)eIdxs[row] * D + c4);
    }
    __syncthreads();

    const float* w1t = W1 + 2 * D * HDIM;          // thread owns h = tid
    float acc[CPS];
#pragma unroll
    for (int c = 0; c < CPS; ++c) acc[c] = 0.f;
    for (int d0 = 0; d0 < D; d0 += 4) {
        float w[4];
#pragma unroll
        for (int j = 0; j < 4; ++j) w[j] = w1t[(d0 + j) * HDIM + tid];  // coalesced
#pragma unroll
        for (int c = 0; c < CPS; ++c) {
            const float4 f = *(const float4*)(&entR[c][d0]);            // broadcast
            acc[c] += f.x * w[0] + f.y * w[1] + f.z * w[2] + f.w * w[3];
        }
    }
    const float phv = phW[tid * PHW + b];
    const float w2v = phW[tid * PHW + 8];
    float sc[CPS];
#pragma unroll
    for (int c = 0; c < CPS; ++c) sc[c] = fmaxf(acc[c] + phv, 0.f) * w2v;

#pragma unroll
    for (int m = 1; m <= 32; m <<= 1)
#pragma unroll
        for (int c = 0; c < CPS; ++c) sc[c] += __shfl_xor(sc[c], m, 64);
    if (lane == 0)
#pragma unroll
        for (int c = 0; c < CPS; ++c) red[wave][c] = sc[c];
    __syncthreads();
    if (tid < CPS) {
        const float v = red[0][tid] + red[1][tid] + red[2][tid] + red[3][tid] + b2[0];
        cand_exact[(size_t)(b * NSHARD + s) * CPS + tid] = sk_encode(v, eIdxs[tid]);
    }
}

// ---------------------------------------------------------------------------
// K4: final top-k per row from 256 exactly-scored keys. 1 block, wave = row.
// ---------------------------------------------------------------------------
__global__ __launch_bounds__(256) void final_kernel(
        const unsigned long long* __restrict__ cand_exact, int k,
        float* __restrict__ out) {
    const int lane = threadIdx.x & 63;
    const int wave = threadIdx.x >> 6;
    for (int b = wave; b < NB; b += 4) {
        unsigned long long lk[4];
#pragma unroll
        for (int j = 0; j < 4; ++j)
            lk[j] = cand_exact[(size_t)b * NCAND + j * 64 + lane];   // coalesced
#pragma unroll
        for (int i = 0; i < 4; ++i)
#pragma unroll
            for (int j = 0; j < 3; ++j)
                if (lk[j] < lk[j + 1]) {
                    const unsigned long long t = lk[j];
                    lk[j] = lk[j + 1];
                    lk[j + 1] = t;
                }
        for (int r = 0; r < k; ++r) {
            const unsigned long long m = wave_max64(lk[0]);
            if (lk[0] == m) {
#pragma unroll
                for (int j = 0; j < 3; ++j) lk[j] = lk[j + 1];
                lk[3] = 0ull;
            }
            if (lane == 0) {
                out[b * k + r] = (float)sk_idx(m);            // indices
                out[NB * k + b * k + r] = sk_val(m);          // scores
            }
        }
    }
}

// ---------------------------------------------------------------------------
extern "C" void kernel_launch(void* const* d_in, const int* in_sizes, int n_in,
                              void* d_out, int out_size, void* d_ws, size_t ws_size,
                              hipStream_t stream) {
    const int*   head     = (const int*)d_in[0];
    const int*   relation = (const int*)d_in[1];
    const float* ent_emb  = (const float*)d_in[3];
    const float* rel_emb  = (const float*)d_in[4];
    const float* W1       = (const float*)d_in[5];
    const float* b1       = (const float*)d_in[6];
    const float* W2       = (const float*)d_in[7];
    const float* b2       = (const float*)d_in[8];

    const int B = in_sizes[0];          // 8
    const int E = in_sizes[3] / D;      // 50000
    int k = out_size / (2 * B);         // 10
    if (k > CPS) k = CPS;

    char* ws = (char*)d_ws;
    unsigned long long* cand_exact = (unsigned long long*)ws;       //  16 KB
    float*          phW       = (float*)(ws + 16384);               //  16 KB
    unsigned short* w1tt      = (unsigned short*)(ws + 32768);      //  64 KB
    float*          scores    = (float*)(ws + 98304);               // 1.6 MB
    float*          out       = (float*)d_out;

    prep_kernel<<<NB + 32, HDIM, 0, stream>>>(head, relation, ent_emb, rel_emb,
                                              W1, b1, W2, phW, w1tt);
    const int nblk = (E + 127) / 128;
    // MEASUREMENT: 4 identical launches. Idempotent (pure function of inputs).
    // dur(R11) - dur(R10) = 3 x score duration.
    score_kernel<<<nblk, 256, 0, stream>>>(ent_emb, w1tt, phW, scores, E);
    score_kernel<<<nblk, 256, 0, stream>>>(ent_emb, w1tt, phW, scores, E);
    score_kernel<<<nblk, 256, 0, stream>>>(ent_emb, w1tt, phW, scores, E);
    score_kernel<<<nblk, 256, 0, stream>>>(ent_emb, w1tt, phW, scores, E);
    topk_rescore_kernel<<<NB * NSHARD, 256, 0, stream>>>(
        scores, E, ent_emb, W1, phW, b2, cand_exact);
    final_kernel<<<1, 256, 0, stream>>>(cand_exact, k, out);
}

// Round 12
// 158.830 us; speedup vs baseline: 1.6515x; 1.6515x over previous
//
#include <hip/hip_runtime.h>

#define D 128
#define HDIM 256
#define NB 8            // batch size (fixed by setup_inputs)
#define NSHARD 16       // topk shards per row
#define CPS 16          // candidates per shard
#define NCAND (NSHARD * CPS)   // 256 candidates per row
#define PHW 16          // phW row stride (floats): [0..7]=ph, [8]=W2
#define WPAD 136        // wL row stride in ushorts (272 B: 16B-aligned, 2-way banks = free)

typedef short bf16x8 __attribute__((ext_vector_type(8)));
typedef float f32x4 __attribute__((ext_vector_type(4)));

__device__ __forceinline__ unsigned short f2bf(float x) {
    unsigned u = __float_as_uint(x);
    unsigned r = u + 0x7FFF + ((u >> 16) & 1);   // RNE (finite data)
    return (unsigned short)(r >> 16);
}
__device__ __forceinline__ bf16x8 pack_bf8(float4 u, float4 v) {
    union { bf16x8 v8; unsigned short s[8]; } r;
    r.s[0] = f2bf(u.x); r.s[1] = f2bf(u.y); r.s[2] = f2bf(u.z); r.s[3] = f2bf(u.w);
    r.s[4] = f2bf(v.x); r.s[5] = f2bf(v.y); r.s[6] = f2bf(v.z); r.s[7] = f2bf(v.w);
    return r.v8;
}

// key = (ordered_float << 32) | (0xFFFFFFFF - idx): max == (max val, min idx)
__device__ __forceinline__ unsigned long long sk_encode(float v, int idx) {
    unsigned u = __float_as_uint(v);
    u = (u & 0x80000000u) ? ~u : (u | 0x80000000u);
    return ((unsigned long long)u << 32) | (unsigned)(0xFFFFFFFFu - (unsigned)idx);
}
__device__ __forceinline__ float sk_val(unsigned long long key) {
    const unsigned u = (unsigned)(key >> 32);
    return (u & 0x80000000u) ? __uint_as_float(u & 0x7FFFFFFFu) : __uint_as_float(~u);
}
__device__ __forceinline__ int sk_idx(unsigned long long key) {
    return (int)(0xFFFFFFFFu - (unsigned)(key & 0xFFFFFFFFu));
}
__device__ __forceinline__ unsigned long long wave_max64(unsigned long long m) {
#pragma unroll
    for (int s = 32; s > 0; s >>= 1) {
        const unsigned long long o = __shfl_xor(m, s, 64);
        if (o > m) m = o;
    }
    return m;
}

// ---------------------------------------------------------------------------
// K1: prep. blocks 0..7: ph row b -> phW[h][b] (+W2 -> phW[h][8] from b==0).
//     blocks 8..39: w1tt = bf16(W1t^T), 4 k-cols each.
// ---------------------------------------------------------------------------
__global__ __launch_bounds__(HDIM) void prep_kernel(
        const int* __restrict__ head, const int* __restrict__ relation,
        const float* __restrict__ ent_emb, const float* __restrict__ rel_emb,
        const float* __restrict__ W1, const float* __restrict__ b1,
        const float* __restrict__ W2, float* __restrict__ phW,
        unsigned short* __restrict__ w1tt) {
    const int w = blockIdx.x;
    const int tid = threadIdx.x;
    if (w < NB) {
        const int b = w;
        const long hidx = head[b];
        const long ridx = relation[b];
        const float* hrow = ent_emb + hidx * D;
        const float* rrow = rel_emb + ridx * D;
        float acc = b1[tid];
#pragma unroll 8
        for (int d = 0; d < D; ++d)
            acc += hrow[d] * W1[d * HDIM + tid];       // coalesced across tid
#pragma unroll 8
        for (int d = 0; d < D; ++d)
            acc += rrow[d] * W1[(D + d) * HDIM + tid];
        phW[tid * PHW + b] = acc;
        if (b == 0) phW[tid * PHW + 8] = W2[tid];
    } else {
        const int k0 = (w - NB) * 4;
        const float* w1t = W1 + 2 * D * HDIM;
        unsigned short pk[4];
#pragma unroll
        for (int j = 0; j < 4; ++j)
            pk[j] = f2bf(w1t[(k0 + j) * HDIM + tid]);  // coalesced across tid
        *(ushort4*)(w1tt + tid * D + k0) = make_ushort4(pk[0], pk[1], pk[2], pk[3]);
    }
}

// ---------------------------------------------------------------------------
// K2: MFMA score with ONE-SHOT LDS staging (R12). Theory: R7-R10 versions had
// every wave privately re-reading 64 KB w1tt + ~48 KB phW through the shared
// per-CU L1, each load spanning 16 non-contiguous cachelines -> the L1/TA
// request pipe was the serialized resource TLP couldn't hide. Now the block
// stages w1tt (69.6 KB, pad 136) + ph transposed [b][h] (8 KB) + w2 (1 KB)
// into LDS ONCE (single barrier), then all fragment reads are ds_read_b128 /
// conflict-free ds_read_b32. 78.8 KB LDS -> 2 blocks/CU. 2 A-tiles per wave.
// mfma_f32_16x16x32_bf16: A[m=lane&15][k=(lane>>4)*8+j]; B[k][n=lane&15];
// C: col(n)=lane&15, row(m)=(lane>>4)*4+reg.
// ---------------------------------------------------------------------------
__global__ __launch_bounds__(256, 2) void score_kernel(
        const float* __restrict__ ent_emb, const unsigned short* __restrict__ w1tt,
        const float* __restrict__ phW, float* __restrict__ scores, int E) {
    __shared__ __align__(16) unsigned short wL[HDIM][WPAD];   // 69.6 KB
    __shared__ float phB[NB][HDIM];                           //  8 KB  [b][h]
    __shared__ float w2L[HDIM];                               //  1 KB

    const int tid = threadIdx.x;
    const int lane = tid & 63;
    const int wave = tid >> 6;
    const int lm = lane & 15;
    const int q = lane >> 4;
    const int base_e = blockIdx.x * 128 + wave * 32;

    // ---- A fragments direct from global (issue first; no LDS dependency) ----
    const float* arow0 = ent_emb + (size_t)min(base_e + lm, E - 1) * D;
    const float* arow1 = ent_emb + (size_t)min(base_e + 16 + lm, E - 1) * D;
    bf16x8 aF0[4], aF1[4];
#pragma unroll
    for (int kk = 0; kk < 4; ++kk) {
        const float4 u0 = *(const float4*)(arow0 + kk * 32 + q * 8);
        const float4 v0 = *(const float4*)(arow0 + kk * 32 + q * 8 + 4);
        aF0[kk] = pack_bf8(u0, v0);
        const float4 u1 = *(const float4*)(arow1 + kk * 32 + q * 8);
        const float4 v1 = *(const float4*)(arow1 + kk * 32 + q * 8 + 4);
        aF1[kk] = pack_bf8(u1, v1);
    }

    // ---- stage w1tt (64 KB) into LDS: 16 iters x 256 threads x 16 B ----
#pragma unroll
    for (int i = 0; i < 16; ++i) {
        const int c = i * 256 + tid;           // chunk of 8 ushorts
        const int row = c >> 4;                // 16 chunks per 128-ushort row
        const int col = (c & 15) << 3;
        *(uint4*)(&wL[row][col]) = *(const uint4*)(w1tt + row * D + col);
    }
    // ---- stage ph (transposed) + w2 ----
    {
        const float4 p0 = *(const float4*)(phW + tid * PHW);
        const float4 p1 = *(const float4*)(phW + tid * PHW + 4);
        phB[0][tid] = p0.x; phB[1][tid] = p0.y; phB[2][tid] = p0.z; phB[3][tid] = p0.w;
        phB[4][tid] = p1.x; phB[5][tid] = p1.y; phB[6][tid] = p1.z; phB[7][tid] = p1.w;
        w2L[tid] = phW[tid * PHW + 8];
    }
    __syncthreads();   // the ONLY barrier

    float sp0[NB * 4], sp1[NB * 4];
#pragma unroll
    for (int i = 0; i < NB * 4; ++i) { sp0[i] = 0.f; sp1[i] = 0.f; }

#pragma unroll
    for (int t = 0; t < 16; ++t) {
        const int h = t * 16 + lm;             // lane's B-row & C-col
        bf16x8 bF[4];
#pragma unroll
        for (int kk = 0; kk < 4; ++kk)
            bF[kk] = *(const bf16x8*)(&wL[h][kk * 32 + q * 8]);   // 2-way banks: free

        float phv[8];
#pragma unroll
        for (int b = 0; b < NB; ++b) phv[b] = phB[b][h];   // 16 banks + broadcast
        const float w2v = w2L[h];

        f32x4 acc0 = (f32x4){0.f, 0.f, 0.f, 0.f};
        f32x4 acc1 = (f32x4){0.f, 0.f, 0.f, 0.f};
#pragma unroll
        for (int kk = 0; kk < 4; ++kk) {
            acc0 = __builtin_amdgcn_mfma_f32_16x16x32_bf16(aF0[kk], bF[kk], acc0, 0, 0, 0);
            acc1 = __builtin_amdgcn_mfma_f32_16x16x32_bf16(aF1[kk], bF[kk], acc1, 0, 0, 0);
        }

#pragma unroll
        for (int b = 0; b < NB; ++b)
#pragma unroll
            for (int r = 0; r < 4; ++r) {
                sp0[b * 4 + r] += fmaxf(phv[b] + acc0[r], 0.f) * w2v;
                sp1[b * 4 + r] += fmaxf(phv[b] + acc1[r], 0.f) * w2v;
            }
    }

    // reduce over the 16 lm lanes (lane bits 0..3)
#pragma unroll
    for (int m = 1; m <= 8; m <<= 1) {
#pragma unroll
        for (int i = 0; i < NB * 4; ++i) {
            sp0[i] += __shfl_xor(sp0[i], m, 64);
            sp1[i] += __shfl_xor(sp1[i], m, 64);
        }
    }
    if (lm == 0) {
#pragma unroll
        for (int r = 0; r < 4; ++r) {
            const int e0 = base_e + q * 4 + r;
            const int e1 = base_e + 16 + q * 4 + r;
            if (e0 < E) {
#pragma unroll
                for (int b = 0; b < NB; ++b)
                    scores[(size_t)b * E + e0] = sp0[b * 4 + r];
            }
            if (e1 < E) {
#pragma unroll
                for (int b = 0; b < NB; ++b)
                    scores[(size_t)b * E + e1] = sp1[b * 4 + r];
            }
        }
    }
}

// ---------------------------------------------------------------------------
// K3: shard top-16 + exact fp32 rescore. 128 blocks = 8 rows x 16 shards.
// ---------------------------------------------------------------------------
__global__ __launch_bounds__(256) void topk_rescore_kernel(
        const float* __restrict__ scores, int E,
        const float* __restrict__ ent_emb, const float* __restrict__ W1,
        const float* __restrict__ phW, const float* __restrict__ b2,
        unsigned long long* __restrict__ cand_exact) {
    const int b = blockIdx.x >> 4;
    const int s = blockIdx.x & 15;
    const int tid = threadIdx.x;
    const int lane = tid & 63;
    const int wave = tid >> 6;

    __shared__ unsigned long long cl[4 * CPS];
    __shared__ unsigned long long candk[CPS];
    __shared__ int eIdxs[CPS];
    __shared__ float entR[CPS][D];                 // 8 KB
    __shared__ float red[4][CPS];

    {
        const int shard = (E + NSHARD - 1) / NSHARD;
        const int start = s * shard;
        const int end = min(E, start + shard);
        const float* row = scores + (size_t)b * E;

        unsigned long long keys[CPS];
#pragma unroll
        for (int i = 0; i < CPS; ++i) keys[i] = 0ull;

        for (int e = start + tid; e < end; e += 256) {
            unsigned long long key = sk_encode(row[e], e);
            if (key > keys[CPS - 1]) {
#pragma unroll
                for (int j = 0; j < CPS; ++j) {
                    const bool gt = key > keys[j];
                    const unsigned long long mx = gt ? key : keys[j];
                    key = gt ? keys[j] : key;
                    keys[j] = mx;
                }
            }
        }
        for (int r = 0; r < CPS; ++r) {
            const unsigned long long m = wave_max64(keys[0]);
            if (keys[0] == m) {
#pragma unroll
                for (int j = 0; j < CPS - 1; ++j) keys[j] = keys[j + 1];
                keys[CPS - 1] = 0ull;
            }
            if (lane == 0) cl[wave * CPS + r] = m;
        }
        __syncthreads();
        if (wave == 0) {
            unsigned long long v = cl[lane];       // 64 candidates
            for (int r = 0; r < CPS; ++r) {
                const unsigned long long m = wave_max64(v);
                if (v == m) v = 0ull;
                if (lane == 0) candk[r] = m;
            }
        }
        __syncthreads();
    }

    if (tid < CPS) eIdxs[tid] = sk_idx(candk[tid]);
    __syncthreads();
    for (int t = tid; t < CPS * (D / 4); t += 256) {
        const int row = t >> 5, c4 = (t & 31) * 4;
        *(float4*)(&entR[row][c4]) =
            *(const float4*)(ent_emb + (size_t)eIdxs[row] * D + c4);
    }
    __syncthreads();

    const float* w1t = W1 + 2 * D * HDIM;          // thread owns h = tid
    float acc[CPS];
#pragma unroll
    for (int c = 0; c < CPS; ++c) acc[c] = 0.f;
    for (int d0 = 0; d0 < D; d0 += 4) {
        float w[4];
#pragma unroll
        for (int j = 0; j < 4; ++j) w[j] = w1t[(d0 + j) * HDIM + tid];  // coalesced
#pragma unroll
        for (int c = 0; c < CPS; ++c) {
            const float4 f = *(const float4*)(&entR[c][d0]);            // broadcast
            acc[c] += f.x * w[0] + f.y * w[1] + f.z * w[2] + f.w * w[3];
        }
    }
    const float phv = phW[tid * PHW + b];
    const float w2v = phW[tid * PHW + 8];
    float sc[CPS];
#pragma unroll
    for (int c = 0; c < CPS; ++c) sc[c] = fmaxf(acc[c] + phv, 0.f) * w2v;

#pragma unroll
    for (int m = 1; m <= 32; m <<= 1)
#pragma unroll
        for (int c = 0; c < CPS; ++c) sc[c] += __shfl_xor(sc[c], m, 64);
    if (lane == 0)
#pragma unroll
        for (int c = 0; c < CPS; ++c) red[wave][c] = sc[c];
    __syncthreads();
    if (tid < CPS) {
        const float v = red[0][tid] + red[1][tid] + red[2][tid] + red[3][tid] + b2[0];
        cand_exact[(size_t)(b * NSHARD + s) * CPS + tid] = sk_encode(v, eIdxs[tid]);
    }
}

// ---------------------------------------------------------------------------
// K4: final top-k per row from 256 exactly-scored keys. 1 block, wave = row.
// ---------------------------------------------------------------------------
__global__ __launch_bounds__(256) void final_kernel(
        const unsigned long long* __restrict__ cand_exact, int k,
        float* __restrict__ out) {
    const int lane = threadIdx.x & 63;
    const int wave = threadIdx.x >> 6;
    for (int b = wave; b < NB; b += 4) {
        unsigned long long lk[4];
#pragma unroll
        for (int j = 0; j < 4; ++j)
            lk[j] = cand_exact[(size_t)b * NCAND + j * 64 + lane];   // coalesced
#pragma unroll
        for (int i = 0; i < 4; ++i)
#pragma unroll
            for (int j = 0; j < 3; ++j)
                if (lk[j] < lk[j + 1]) {
                    const unsigned long long t = lk[j];
                    lk[j] = lk[j + 1];
                    lk[j + 1] = t;
                }
        for (int r = 0; r < k; ++r) {
            const unsigned long long m = wave_max64(lk[0]);
            if (lk[0] == m) {
#pragma unroll
                for (int j = 0; j < 3; ++j) lk[j] = lk[j + 1];
                lk[3] = 0ull;
            }
            if (lane == 0) {
                out[b * k + r] = (float)sk_idx(m);            // indices
                out[NB * k + b * k + r] = sk_val(m);          // scores
            }
        }
    }
}

// ---------------------------------------------------------------------------
extern "C" void kernel_launch(void* const* d_in, const int* in_sizes, int n_in,
                              void* d_out, int out_size, void* d_ws, size_t ws_size,
                              hipStream_t stream) {
    const int*   head     = (const int*)d_in[0];
    const int*   relation = (const int*)d_in[1];
    const float* ent_emb  = (const float*)d_in[3];
    const float* rel_emb  = (const float*)d_in[4];
    const float* W1       = (const float*)d_in[5];
    const float* b1       = (const float*)d_in[6];
    const float* W2       = (const float*)d_in[7];
    const float* b2       = (const float*)d_in[8];

    const int B = in_sizes[0];          // 8
    const int E = in_sizes[3] / D;      // 50000
    int k = out_size / (2 * B);         // 10
    if (k > CPS) k = CPS;

    char* ws = (char*)d_ws;
    unsigned long long* cand_exact = (unsigned long long*)ws;       //  16 KB
    float*          phW       = (float*)(ws + 16384);               //  16 KB
    unsigned short* w1tt      = (unsigned short*)(ws + 32768);      //  64 KB
    float*          scores    = (float*)(ws + 98304);               // 1.6 MB
    float*          out       = (float*)d_out;

    prep_kernel<<<NB + 32, HDIM, 0, stream>>>(head, relation, ent_emb, rel_emb,
                                              W1, b1, W2, phW, w1tt);
    const int nblk = (E + 127) / 128;
    score_kernel<<<nblk, 256, 0, stream>>>(ent_emb, w1tt, phW, scores, E);
    topk_rescore_kernel<<<NB * NSHARD, 256, 0, stream>>>(
        scores, E, ent_emb, W1, phW, b2, cand_exact);
    final_kernel<<<1, 256, 0, stream>>>(cand_exact, k, out);
}

// Round 13
// 155.573 us; speedup vs baseline: 1.6860x; 1.0209x over previous
//
#include <hip/hip_runtime.h>

#define D 128
#define HDIM 256
#define NB 8            // batch size (fixed by setup_inputs)
#define NSHARD 16       // topk shards per row
#define CPS 16          // candidates per shard
#define NCAND (NSHARD * CPS)   // 256 candidates per row
#define PHW 16          // phW row stride (floats): [0..7]=ph, [8]=W2
#define WPAD 136        // wL row stride in ushorts (272 B: 16B-aligned, 2-way banks = free)

typedef short bf16x8 __attribute__((ext_vector_type(8)));
typedef float f32x4 __attribute__((ext_vector_type(4)));

__device__ __forceinline__ unsigned short f2bf(float x) {
    unsigned u = __float_as_uint(x);
    unsigned r = u + 0x7FFF + ((u >> 16) & 1);   // RNE (finite data)
    return (unsigned short)(r >> 16);
}
__device__ __forceinline__ bf16x8 pack_bf8(float4 u, float4 v) {
    union { bf16x8 v8; unsigned short s[8]; } r;
    r.s[0] = f2bf(u.x); r.s[1] = f2bf(u.y); r.s[2] = f2bf(u.z); r.s[3] = f2bf(u.w);
    r.s[4] = f2bf(v.x); r.s[5] = f2bf(v.y); r.s[6] = f2bf(v.z); r.s[7] = f2bf(v.w);
    return r.v8;
}

// key = (ordered_float << 32) | (0xFFFFFFFF - idx): max == (max val, min idx)
__device__ __forceinline__ unsigned long long sk_encode(float v, int idx) {
    unsigned u = __float_as_uint(v);
    u = (u & 0x80000000u) ? ~u : (u | 0x80000000u);
    return ((unsigned long long)u << 32) | (unsigned)(0xFFFFFFFFu - (unsigned)idx);
}
__device__ __forceinline__ float sk_val(unsigned long long key) {
    const unsigned u = (unsigned)(key >> 32);
    return (u & 0x80000000u) ? __uint_as_float(u & 0x7FFFFFFFu) : __uint_as_float(~u);
}
__device__ __forceinline__ int sk_idx(unsigned long long key) {
    return (int)(0xFFFFFFFFu - (unsigned)(key & 0xFFFFFFFFu));
}
__device__ __forceinline__ unsigned long long wave_max64(unsigned long long m) {
#pragma unroll
    for (int s = 32; s > 0; s >>= 1) {
        const unsigned long long o = __shfl_xor(m, s, 64);
        if (o > m) m = o;
    }
    return m;
}

// ---------------------------------------------------------------------------
// K1: prep. blocks 0..7: ph row b -> phW[h][b] (+W2 -> phW[h][8] from b==0).
//     blocks 8..39: w1tt = bf16(W1t^T), 4 k-cols each.
// ---------------------------------------------------------------------------
__global__ __launch_bounds__(HDIM) void prep_kernel(
        const int* __restrict__ head, const int* __restrict__ relation,
        const float* __restrict__ ent_emb, const float* __restrict__ rel_emb,
        const float* __restrict__ W1, const float* __restrict__ b1,
        const float* __restrict__ W2, float* __restrict__ phW,
        unsigned short* __restrict__ w1tt) {
    const int w = blockIdx.x;
    const int tid = threadIdx.x;
    if (w < NB) {
        const int b = w;
        const long hidx = head[b];
        const long ridx = relation[b];
        const float* hrow = ent_emb + hidx * D;
        const float* rrow = rel_emb + ridx * D;
        float acc = b1[tid];
#pragma unroll 8
        for (int d = 0; d < D; ++d)
            acc += hrow[d] * W1[d * HDIM + tid];       // coalesced across tid
#pragma unroll 8
        for (int d = 0; d < D; ++d)
            acc += rrow[d] * W1[(D + d) * HDIM + tid];
        phW[tid * PHW + b] = acc;
        if (b == 0) phW[tid * PHW + 8] = W2[tid];
    } else {
        const int k0 = (w - NB) * 4;
        const float* w1t = W1 + 2 * D * HDIM;
        unsigned short pk[4];
#pragma unroll
        for (int j = 0; j < 4; ++j)
            pk[j] = f2bf(w1t[(k0 + j) * HDIM + tid]);  // coalesced across tid
        *(ushort4*)(w1tt + tid * D + k0) = make_ushort4(pk[0], pk[1], pk[2], pk[3]);
    }
}

// ---------------------------------------------------------------------------
// K2: MFMA score, LDS-staged (R12), now 512 threads / 8 waves per block with
// ONE 16-entity A-tile per wave (R13). Same 128 entities/block and same LDS
// (78.8 KB -> 2 blocks/CU), but waves/CU goes ~6 -> ~16 (4/SIMD): the serial
// stage->barrier->[ds_read->MFMA->epilogue] chain is now hidden by TLP.
// __launch_bounds__(512,4) pins <=128 VGPR so registers can't undercut the
// LDS-limited occupancy.
// mfma_f32_16x16x32_bf16: A[m=lane&15][k=(lane>>4)*8+j]; B[k][n=lane&15];
// C: col(n)=lane&15, row(m)=(lane>>4)*4+reg.
// ---------------------------------------------------------------------------
__global__ __launch_bounds__(512, 4) void score_kernel(
        const float* __restrict__ ent_emb, const unsigned short* __restrict__ w1tt,
        const float* __restrict__ phW, float* __restrict__ scores, int E) {
    __shared__ __align__(16) unsigned short wL[HDIM][WPAD];   // 69.6 KB
    __shared__ float phB[NB][HDIM];                           //  8 KB  [b][h]
    __shared__ float w2L[HDIM];                               //  1 KB

    const int tid = threadIdx.x;
    const int lane = tid & 63;
    const int wave = tid >> 6;          // 0..7
    const int lm = lane & 15;
    const int q = lane >> 4;
    const int base_e = blockIdx.x * 128 + wave * 16;

    // ---- A fragments direct from global (issue first; no LDS dependency) ----
    const float* arow = ent_emb + (size_t)min(base_e + lm, E - 1) * D;
    bf16x8 aF[4];
#pragma unroll
    for (int kk = 0; kk < 4; ++kk) {
        const float4 u = *(const float4*)(arow + kk * 32 + q * 8);
        const float4 v = *(const float4*)(arow + kk * 32 + q * 8 + 4);
        aF[kk] = pack_bf8(u, v);
    }

    // ---- stage w1tt (64 KB) into LDS: 8 iters x 512 threads x 16 B ----
#pragma unroll
    for (int i = 0; i < 8; ++i) {
        const int c = i * 512 + tid;           // chunk of 8 ushorts
        const int row = c >> 4;                // 16 chunks per 128-ushort row
        const int col = (c & 15) << 3;
        *(uint4*)(&wL[row][col]) = *(const uint4*)(w1tt + row * D + col);
    }
    // ---- stage ph (transposed) + w2 ----
    if (tid < HDIM) {
        const float4 p0 = *(const float4*)(phW + tid * PHW);
        const float4 p1 = *(const float4*)(phW + tid * PHW + 4);
        phB[0][tid] = p0.x; phB[1][tid] = p0.y; phB[2][tid] = p0.z; phB[3][tid] = p0.w;
        phB[4][tid] = p1.x; phB[5][tid] = p1.y; phB[6][tid] = p1.z; phB[7][tid] = p1.w;
        w2L[tid] = phW[tid * PHW + 8];
    }
    __syncthreads();   // the ONLY barrier

    float sp[NB * 4];
#pragma unroll
    for (int i = 0; i < NB * 4; ++i) sp[i] = 0.f;

#pragma unroll
    for (int t = 0; t < 16; ++t) {
        const int h = t * 16 + lm;             // lane's B-row & C-col
        bf16x8 bF[4];
#pragma unroll
        for (int kk = 0; kk < 4; ++kk)
            bF[kk] = *(const bf16x8*)(&wL[h][kk * 32 + q * 8]);   // 2-way banks: free

        float phv[8];
#pragma unroll
        for (int b = 0; b < NB; ++b) phv[b] = phB[b][h];   // 16 banks + broadcast
        const float w2v = w2L[h];

        f32x4 acc = (f32x4){0.f, 0.f, 0.f, 0.f};
#pragma unroll
        for (int kk = 0; kk < 4; ++kk)
            acc = __builtin_amdgcn_mfma_f32_16x16x32_bf16(aF[kk], bF[kk], acc, 0, 0, 0);

#pragma unroll
        for (int b = 0; b < NB; ++b)
#pragma unroll
            for (int r = 0; r < 4; ++r)
                sp[b * 4 + r] += fmaxf(phv[b] + acc[r], 0.f) * w2v;
    }

    // reduce over the 16 lm lanes (lane bits 0..3)
#pragma unroll
    for (int m = 1; m <= 8; m <<= 1) {
#pragma unroll
        for (int i = 0; i < NB * 4; ++i)
            sp[i] += __shfl_xor(sp[i], m, 64);
    }
    if (lm == 0) {
#pragma unroll
        for (int r = 0; r < 4; ++r) {
            const int e = base_e + q * 4 + r;
            if (e < E) {
#pragma unroll
                for (int b = 0; b < NB; ++b)
                    scores[(size_t)b * E + e] = sp[b * 4 + r];
            }
        }
    }
}

// ---------------------------------------------------------------------------
// K3: shard top-16 + exact fp32 rescore. 128 blocks = 8 rows x 16 shards.
// ---------------------------------------------------------------------------
__global__ __launch_bounds__(256) void topk_rescore_kernel(
        const float* __restrict__ scores, int E,
        const float* __restrict__ ent_emb, const float* __restrict__ W1,
        const float* __restrict__ phW, const float* __restrict__ b2,
        unsigned long long* __restrict__ cand_exact) {
    const int b = blockIdx.x >> 4;
    const int s = blockIdx.x & 15;
    const int tid = threadIdx.x;
    const int lane = tid & 63;
    const int wave = tid >> 6;

    __shared__ unsigned long long cl[4 * CPS];
    __shared__ unsigned long long candk[CPS];
    __shared__ int eIdxs[CPS];
    __shared__ float entR[CPS][D];                 // 8 KB
    __shared__ float red[4][CPS];

    {
        const int shard = (E + NSHARD - 1) / NSHARD;
        const int start = s * shard;
        const int end = min(E, start + shard);
        const float* row = scores + (size_t)b * E;

        unsigned long long keys[CPS];
#pragma unroll
        for (int i = 0; i < CPS; ++i) keys[i] = 0ull;

        for (int e = start + tid; e < end; e += 256) {
            unsigned long long key = sk_encode(row[e], e);
            if (key > keys[CPS - 1]) {
#pragma unroll
                for (int j = 0; j < CPS; ++j) {
                    const bool gt = key > keys[j];
                    const unsigned long long mx = gt ? key : keys[j];
                    key = gt ? keys[j] : key;
                    keys[j] = mx;
                }
            }
        }
        for (int r = 0; r < CPS; ++r) {
            const unsigned long long m = wave_max64(keys[0]);
            if (keys[0] == m) {
#pragma unroll
                for (int j = 0; j < CPS - 1; ++j) keys[j] = keys[j + 1];
                keys[CPS - 1] = 0ull;
            }
            if (lane == 0) cl[wave * CPS + r] = m;
        }
        __syncthreads();
        if (wave == 0) {
            unsigned long long v = cl[lane];       // 64 candidates
            for (int r = 0; r < CPS; ++r) {
                const unsigned long long m = wave_max64(v);
                if (v == m) v = 0ull;
                if (lane == 0) candk[r] = m;
            }
        }
        __syncthreads();
    }

    if (tid < CPS) eIdxs[tid] = sk_idx(candk[tid]);
    __syncthreads();
    for (int t = tid; t < CPS * (D / 4); t += 256) {
        const int row = t >> 5, c4 = (t & 31) * 4;
        *(float4*)(&entR[row][c4]) =
            *(const float4*)(ent_emb + (size_t)eIdxs[row] * D + c4);
    }
    __syncthreads();

    const float* w1t = W1 + 2 * D * HDIM;          // thread owns h = tid
    float acc[CPS];
#pragma unroll
    for (int c = 0; c < CPS; ++c) acc[c] = 0.f;
    for (int d0 = 0; d0 < D; d0 += 4) {
        float w[4];
#pragma unroll
        for (int j = 0; j < 4; ++j) w[j] = w1t[(d0 + j) * HDIM + tid];  // coalesced
#pragma unroll
        for (int c = 0; c < CPS; ++c) {
            const float4 f = *(const float4*)(&entR[c][d0]);            // broadcast
            acc[c] += f.x * w[0] + f.y * w[1] + f.z * w[2] + f.w * w[3];
        }
    }
    const float phv = phW[tid * PHW + b];
    const float w2v = phW[tid * PHW + 8];
    float sc[CPS];
#pragma unroll
    for (int c = 0; c < CPS; ++c) sc[c] = fmaxf(acc[c] + phv, 0.f) * w2v;

#pragma unroll
    for (int m = 1; m <= 32; m <<= 1)
#pragma unroll
        for (int c = 0; c < CPS; ++c) sc[c] += __shfl_xor(sc[c], m, 64);
    if (lane == 0)
#pragma unroll
        for (int c = 0; c < CPS; ++c) red[wave][c] = sc[c];
    __syncthreads();
    if (tid < CPS) {
        const float v = red[0][tid] + red[1][tid] + red[2][tid] + red[3][tid] + b2[0];
        cand_exact[(size_t)(b * NSHARD + s) * CPS + tid] = sk_encode(v, eIdxs[tid]);
    }
}

// ---------------------------------------------------------------------------
// K4: final top-k per row from 256 exactly-scored keys. 1 block, wave = row.
// ---------------------------------------------------------------------------
__global__ __launch_bounds__(256) void final_kernel(
        const unsigned long long* __restrict__ cand_exact, int k,
        float* __restrict__ out) {
    const int lane = threadIdx.x & 63;
    const int wave = threadIdx.x >> 6;
    for (int b = wave; b < NB; b += 4) {
        unsigned long long lk[4];
#pragma unroll
        for (int j = 0; j < 4; ++j)
            lk[j] = cand_exact[(size_t)b * NCAND + j * 64 + lane];   // coalesced
#pragma unroll
        for (int i = 0; i < 4; ++i)
#pragma unroll
            for (int j = 0; j < 3; ++j)
                if (lk[j] < lk[j + 1]) {
                    const unsigned long long t = lk[j];
                    lk[j] = lk[j + 1];
                    lk[j + 1] = t;
                }
        for (int r = 0; r < k; ++r) {
            const unsigned long long m = wave_max64(lk[0]);
            if (lk[0] == m) {
#pragma unroll
                for (int j = 0; j < 3; ++j) lk[j] = lk[j + 1];
                lk[3] = 0ull;
            }
            if (lane == 0) {
                out[b * k + r] = (float)sk_idx(m);            // indices
                out[NB * k + b * k + r] = sk_val(m);          // scores
            }
        }
    }
}

// ---------------------------------------------------------------------------
extern "C" void kernel_launch(void* const* d_in, const int* in_sizes, int n_in,
                              void* d_out, int out_size, void* d_ws, size_t ws_size,
                              hipStream_t stream) {
    const int*   head     = (const int*)d_in[0];
    const int*   relation = (const int*)d_in[1];
    const float* ent_emb  = (const float*)d_in[3];
    const float* rel_emb  = (const float*)d_in[4];
    const float* W1       = (const float*)d_in[5];
    const float* b1       = (const float*)d_in[6];
    const float* W2       = (const float*)d_in[7];
    const float* b2       = (const float*)d_in[8];

    const int B = in_sizes[0];          // 8
    const int E = in_sizes[3] / D;      // 50000
    int k = out_size / (2 * B);         // 10
    if (k > CPS) k = CPS;

    char* ws = (char*)d_ws;
    unsigned long long* cand_exact = (unsigned long long*)ws;       //  16 KB
    float*          phW       = (float*)(ws + 16384);               //  16 KB
    unsigned short* w1tt      = (unsigned short*)(ws + 32768);      //  64 KB
    float*          scores    = (float*)(ws + 98304);               // 1.6 MB
    float*          out       = (float*)d_out;

    prep_kernel<<<NB + 32, HDIM, 0, stream>>>(head, relation, ent_emb, rel_emb,
                                              W1, b1, W2, phW, w1tt);
    const int nblk = (E + 127) / 128;
    score_kernel<<<nblk, 512, 0, stream>>>(ent_emb, w1tt, phW, scores, E);
    topk_rescore_kernel<<<NB * NSHARD, 256, 0, stream>>>(
        scores, E, ent_emb, W1, phW, b2, cand_exact);
    final_kernel<<<1, 256, 0, stream>>>(cand_exact, k, out);
}